// Round 2
// baseline (6287.076 us; speedup 1.0000x reference)
//
#include <hip/hip_runtime.h>
#include <cmath>

#define TPB 256

// ---------------- CSR build ----------------

__global__ void hist_kernel(const int* __restrict__ rows, int E, int* __restrict__ counts) {
  int i = blockIdx.x * TPB + threadIdx.x;
  if (i < E) atomicAdd(&counts[rows[i]], 1);
}

// scan over M counts -> P[0..M] (P[0]=0 after scan3), chunk = 2048/block
__global__ void scan1_kernel(const int* __restrict__ counts, int M,
                             int* __restrict__ P, int* __restrict__ S) {
  __shared__ int lds[TPB];
  int base = blockIdx.x * 2048 + threadIdx.x * 8;
  int v[8];
  int run = 0;
#pragma unroll
  for (int i = 0; i < 8; ++i) {
    int idx = base + i;
    int c = (idx < M) ? counts[idx] : 0;
    run += c;
    v[i] = run;
  }
  lds[threadIdx.x] = run;
  __syncthreads();
  for (int off = 1; off < TPB; off <<= 1) {
    int t = 0;
    if ((int)threadIdx.x >= off) t = lds[threadIdx.x - off];
    __syncthreads();
    if ((int)threadIdx.x >= off) lds[threadIdx.x] += t;
    __syncthreads();
  }
  int excl = (threadIdx.x > 0) ? lds[threadIdx.x - 1] : 0;
#pragma unroll
  for (int i = 0; i < 8; ++i) {
    int idx = base + i;
    if (idx < M) P[idx + 1] = v[i] + excl;
  }
  if (threadIdx.x == TPB - 1) S[blockIdx.x] = lds[TPB - 1];
}

__global__ void scan2_kernel(int* __restrict__ S, int NB) {
  __shared__ int lds[TPB];
  int carry = 0;
  for (int b0 = 0; b0 < NB; b0 += TPB) {
    int i = b0 + threadIdx.x;
    int val = (i < NB) ? S[i] : 0;
    lds[threadIdx.x] = val;
    __syncthreads();
    for (int off = 1; off < TPB; off <<= 1) {
      int t = 0;
      if ((int)threadIdx.x >= off) t = lds[threadIdx.x - off];
      __syncthreads();
      if ((int)threadIdx.x >= off) lds[threadIdx.x] += t;
      __syncthreads();
    }
    int inc = lds[threadIdx.x];
    int tot = lds[TPB - 1];
    if (i < NB) S[i] = inc + carry;
    carry += tot;
    __syncthreads();
  }
}

__global__ void scan3_kernel(int* __restrict__ P, const int* __restrict__ S, int M) {
  int b = blockIdx.x;
  int add = (b == 0) ? 0 : S[b - 1];
  int base = b * 2048;
  for (int i = threadIdx.x; i < 2048; i += TPB) {
    int idx = base + i;
    if (idx < M) P[idx + 1] += add;
  }
  if (b == 0 && threadIdx.x == 0) P[0] = 0;
}

__global__ void copy_int_kernel(const int* __restrict__ src, int* __restrict__ dst, int M) {
  int i = blockIdx.x * TPB + threadIdx.x;
  if (i < M) dst[i] = src[i];
}

__global__ void scatter_kernel(const int* __restrict__ rows, const int* __restrict__ cols,
                               const float* __restrict__ vals, int E,
                               int* __restrict__ cursor, int2* __restrict__ pairs) {
  int i = blockIdx.x * TPB + threadIdx.x;
  if (i < E) {
    int r = rows[i];
    int pos = atomicAdd(&cursor[r], 1);
    pairs[pos] = make_int2(cols[i], __float_as_int(vals[i]));
  }
}

// ---------------- dense GEMM: C[nrows,128] = A @ W (+bias) ----------------
// block 256 thr, tile 128 rows x 128 cols, thread 8x8.
// W staged in 16 KB LDS chunks (k-depth 32) -> up to 8 blocks/CU (32 waves).
// Thread's 8 cols split {cg*4, 64+cg*4}: 16 lanes sweep all 32 banks -> 2-way
// LDS aliasing only (free per m136), vs 4-way for cg*8.

__global__ __launch_bounds__(TPB) void gemm128_kernel(
    const float* __restrict__ A, const float* __restrict__ W,
    const float* __restrict__ bias, float* __restrict__ C, int nrows) {
  __shared__ float sW[32 * 128];
  const int cg = threadIdx.x & 15;
  const int rg = threadIdx.x >> 4;
  const int cA = cg * 4, cB = 64 + cg * 4;
  const int row0 = blockIdx.x * 128 + rg * 8;
  float acc[8][8];
#pragma unroll
  for (int j = 0; j < 8; ++j)
#pragma unroll
    for (int i = 0; i < 8; ++i) acc[j][i] = 0.f;

  for (int kc = 0; kc < 128; kc += 32) {
    for (int i = threadIdx.x * 4; i < 32 * 128; i += TPB * 4)
      *(float4*)&sW[i] = *(const float4*)&W[kc * 128 + i];
    __syncthreads();
#pragma unroll
    for (int k4 = 0; k4 < 32; k4 += 4) {
      float4 a[8];
#pragma unroll
      for (int j = 0; j < 8; ++j) {
        int r = row0 + j;
        a[j] = (r < nrows) ? *(const float4*)&A[(size_t)r * 128 + kc + k4]
                           : make_float4(0.f, 0.f, 0.f, 0.f);
      }
#pragma unroll
      for (int kk = 0; kk < 4; ++kk) {
        float4 w0 = *(const float4*)&sW[(k4 + kk) * 128 + cA];
        float4 w1 = *(const float4*)&sW[(k4 + kk) * 128 + cB];
#pragma unroll
        for (int j = 0; j < 8; ++j) {
          float aj = (kk == 0) ? a[j].x : (kk == 1) ? a[j].y : (kk == 2) ? a[j].z : a[j].w;
          acc[j][0] = fmaf(aj, w0.x, acc[j][0]);
          acc[j][1] = fmaf(aj, w0.y, acc[j][1]);
          acc[j][2] = fmaf(aj, w0.z, acc[j][2]);
          acc[j][3] = fmaf(aj, w0.w, acc[j][3]);
          acc[j][4] = fmaf(aj, w1.x, acc[j][4]);
          acc[j][5] = fmaf(aj, w1.y, acc[j][5]);
          acc[j][6] = fmaf(aj, w1.z, acc[j][6]);
          acc[j][7] = fmaf(aj, w1.w, acc[j][7]);
        }
      }
    }
    __syncthreads();
  }
  float bv[8];
  if (bias) {
    *(float4*)&bv[0] = *(const float4*)&bias[cA];
    *(float4*)&bv[4] = *(const float4*)&bias[cB];
  } else {
#pragma unroll
    for (int i = 0; i < 8; ++i) bv[i] = 0.f;
  }
#pragma unroll
  for (int j = 0; j < 8; ++j) {
    int r = row0 + j;
    if (r < nrows) {
      *(float4*)&C[(size_t)r * 128 + cA] =
          make_float4(acc[j][0] + bv[0], acc[j][1] + bv[1], acc[j][2] + bv[2], acc[j][3] + bv[3]);
      *(float4*)&C[(size_t)r * 128 + cB] =
          make_float4(acc[j][4] + bv[4], acc[j][5] + bv[5], acc[j][6] + bv[6], acc[j][7] + bv[7]);
    }
  }
}

// ---------------- fusion: score[v][n] = w2 . tanh(x[v,n,:] @ W1 + b1) ----------------

__global__ __launch_bounds__(TPB) void fusion_score_kernel(
    const float* __restrict__ x, const float* __restrict__ W1,
    const float* __restrict__ b1, const float* __restrict__ w2,
    float* __restrict__ score, int nrows) {
  __shared__ float sW[32 * 128];
  const int v = blockIdx.y;
  const float* A = x + (size_t)v * nrows * 128;
  const int cg = threadIdx.x & 15;
  const int rg = threadIdx.x >> 4;
  const int cA = cg * 4, cB = 64 + cg * 4;
  const int row0 = blockIdx.x * 128 + rg * 8;
  float acc[8][8];
#pragma unroll
  for (int j = 0; j < 8; ++j)
#pragma unroll
    for (int i = 0; i < 8; ++i) acc[j][i] = 0.f;

  for (int kc = 0; kc < 128; kc += 32) {
    for (int i = threadIdx.x * 4; i < 32 * 128; i += TPB * 4)
      *(float4*)&sW[i] = *(const float4*)&W1[kc * 128 + i];
    __syncthreads();
#pragma unroll
    for (int k4 = 0; k4 < 32; k4 += 4) {
      float4 a[8];
#pragma unroll
      for (int j = 0; j < 8; ++j) {
        int r = row0 + j;
        a[j] = (r < nrows) ? *(const float4*)&A[(size_t)r * 128 + kc + k4]
                           : make_float4(0.f, 0.f, 0.f, 0.f);
      }
#pragma unroll
      for (int kk = 0; kk < 4; ++kk) {
        float4 w0 = *(const float4*)&sW[(k4 + kk) * 128 + cA];
        float4 w1 = *(const float4*)&sW[(k4 + kk) * 128 + cB];
#pragma unroll
        for (int j = 0; j < 8; ++j) {
          float aj = (kk == 0) ? a[j].x : (kk == 1) ? a[j].y : (kk == 2) ? a[j].z : a[j].w;
          acc[j][0] = fmaf(aj, w0.x, acc[j][0]);
          acc[j][1] = fmaf(aj, w0.y, acc[j][1]);
          acc[j][2] = fmaf(aj, w0.z, acc[j][2]);
          acc[j][3] = fmaf(aj, w0.w, acc[j][3]);
          acc[j][4] = fmaf(aj, w1.x, acc[j][4]);
          acc[j][5] = fmaf(aj, w1.y, acc[j][5]);
          acc[j][6] = fmaf(aj, w1.z, acc[j][6]);
          acc[j][7] = fmaf(aj, w1.w, acc[j][7]);
        }
      }
    }
    __syncthreads();
  }
  float bb[8], ww[8];
  *(float4*)&bb[0] = *(const float4*)&b1[cA];
  *(float4*)&bb[4] = *(const float4*)&b1[cB];
  *(float4*)&ww[0] = *(const float4*)&w2[cA];
  *(float4*)&ww[4] = *(const float4*)&w2[cB];
#pragma unroll
  for (int j = 0; j < 8; ++j) {
    float p = 0.f;
#pragma unroll
    for (int i = 0; i < 8; ++i) p += tanhf(acc[j][i] + bb[i]) * ww[i];
#pragma unroll
    for (int off = 8; off > 0; off >>= 1) p += __shfl_down(p, off, 16);
    if (cg == 0 && row0 + j < nrows) score[(size_t)v * nrows + row0 + j] = p;
  }
}

// softmax over 2 views + weighted sum (b2 cancels in the 2-way softmax)
__global__ void combine_kernel(const float* __restrict__ x, const float* __restrict__ score,
                               float* __restrict__ fused, int nrows) {
  int i = blockIdx.x * TPB + threadIdx.x;  // over nrows*32 float4s
  if (i >= nrows * 32) return;
  int n = i >> 5;
  float s0 = score[n], s1 = score[nrows + n];
  float m = fmaxf(s0, s1);
  float e0 = expf(s0 - m), e1 = expf(s1 - m);
  float inv = 1.f / (e0 + e1);
  float w0 = e0 * inv, w1 = e1 * inv;
  float4 a = ((const float4*)x)[i];
  float4 b = ((const float4*)x)[(size_t)nrows * 32 + i];
  ((float4*)fused)[i] = make_float4(w0 * a.x + w1 * b.x, w0 * a.y + w1 * b.y,
                                    w0 * a.z + w1 * b.z, w0 * a.w + w1 * b.w);
}

// ---------------- spmm: y[r,:] = (relu?) sum val * x[col,:] (+add0 +add1) ----------------
// one 32-lane half-wave per row; lanes hold float4 (128 cols / 32 lanes).
// Per wave-instr: 1 gather serves 2 nnz (1 KB), 1 shfl serves 2 nnz — half the
// instruction count of the wave-per-row/float2 version at identical bytes.

__global__ __launch_bounds__(TPB) void spmm_kernel(
    const int* __restrict__ ptr, const int2* __restrict__ pairs,
    const float* __restrict__ x, float* __restrict__ y, int nrows, int do_relu,
    const float* __restrict__ add0, const float* __restrict__ add1) {
  int row = (blockIdx.x * TPB + threadIdx.x) >> 5;
  int hl = threadIdx.x & 31;
  if (row >= nrows) return;
  int start = ptr[row], end = ptr[row + 1];
  float ax = 0.f, ay = 0.f, az = 0.f, aw = 0.f;
  for (int j = start; j < end; j += 32) {
    int nrem = end - j;
    if (nrem > 32) nrem = 32;
    int2 pr = make_int2(0, 0);
    if (hl < nrem) pr = pairs[j + hl];
    for (int t = 0; t < nrem; ++t) {
      int c = __shfl(pr.x, t, 32);
      float v = __int_as_float(__shfl(pr.y, t, 32));
      const float4 xv = *(const float4*)&x[(size_t)c * 128 + hl * 4];
      ax = fmaf(v, xv.x, ax);
      ay = fmaf(v, xv.y, ay);
      az = fmaf(v, xv.z, az);
      aw = fmaf(v, xv.w, aw);
    }
  }
  if (do_relu) {
    ax = fmaxf(ax, 0.f); ay = fmaxf(ay, 0.f);
    az = fmaxf(az, 0.f); aw = fmaxf(aw, 0.f);
  }
  size_t o = (size_t)row * 128 + hl * 4;
  if (add0) { float4 t = *(const float4*)&add0[o]; ax += t.x; ay += t.y; az += t.z; aw += t.w; }
  if (add1) { float4 t = *(const float4*)&add1[o]; ax += t.x; ay += t.y; az += t.z; aw += t.w; }
  *(float4*)&y[o] = make_float4(ax, ay, az, aw);
}

// ---------------- launch ----------------

extern "C" void kernel_launch(void* const* d_in, const int* in_sizes, int n_in,
                              void* d_out, int out_size, void* d_ws, size_t ws_size,
                              hipStream_t stream) {
  const float* x   = (const float*)d_in[0];
  const float* fw1 = (const float*)d_in[1];
  const float* fb1 = (const float*)d_in[2];
  const float* fw2 = (const float*)d_in[3];
  // d_in[4] = fusion_b2: cancels in 2-way softmax
  const float* hgw = (const float*)d_in[5];
  const float* lgw = (const float*)d_in[6];
  const float* lgb = (const float*)d_in[7];
  const float* c1v = (const float*)d_in[8];
  const float* c2v = (const float*)d_in[9];
  const float* lgv = (const float*)d_in[10];
  const int* c1r = (const int*)d_in[11];
  const int* c1c = (const int*)d_in[12];
  const int* c2r = (const int*)d_in[13];
  const int* c2c = (const int*)d_in[14];
  const int* lgr = (const int*)d_in[15];
  const int* lgc = (const int*)d_in[16];

  const int N = in_sizes[0] / 256;  // x is [2,N,128]
  const int E = in_sizes[8];
  const int M = 3 * N;

  char* ws = (char*)d_ws;
  size_t off = 0;
  auto alloc = [&](size_t bytes) -> void* {
    void* p = ws + off;
    off += (bytes + 511) & ~(size_t)511;
    return p;
  };
  int* P      = (int*)alloc((size_t)(M + 1) * 4);
  int* S      = (int*)alloc((size_t)4096 * 4);
  int* Q      = (int*)alloc((size_t)M * 4);
  int* counts = (int*)alloc((size_t)M * 4);
  int2* pairs = (int2*)alloc((size_t)3 * E * 8);
  float* score = (float*)alloc((size_t)2 * N * 4);
  float* F0 = (float*)alloc((size_t)N * 128 * 4);
  float* F1 = (float*)alloc((size_t)N * 128 * 4);
  float* F2 = (float*)alloc((size_t)N * 128 * 4);
  float* outH = (float*)d_out;
  float* outA = (float*)d_out + (size_t)N * 128;

  // ---- CSR build for [coef1 | coef2 | lg] concatenated ----
  hipMemsetAsync(counts, 0, (size_t)M * 4, stream);
  int gE = (E + TPB - 1) / TPB;
  hist_kernel<<<gE, TPB, 0, stream>>>(c1r, E, counts + 0);
  hist_kernel<<<gE, TPB, 0, stream>>>(c2r, E, counts + N);
  hist_kernel<<<gE, TPB, 0, stream>>>(lgr, E, counts + 2 * N);
  int NB = (M + 2047) / 2048;
  scan1_kernel<<<NB, TPB, 0, stream>>>(counts, M, P, S);
  scan2_kernel<<<1, TPB, 0, stream>>>(S, NB);
  scan3_kernel<<<NB, TPB, 0, stream>>>(P, S, M);
  copy_int_kernel<<<(M + TPB - 1) / TPB, TPB, 0, stream>>>(P, Q, M);
  scatter_kernel<<<gE, TPB, 0, stream>>>(c1r, c1c, c1v, E, Q + 0, pairs);
  scatter_kernel<<<gE, TPB, 0, stream>>>(c2r, c2c, c2v, E, Q + N, pairs);
  scatter_kernel<<<gE, TPB, 0, stream>>>(lgr, lgc, lgv, E, Q + 2 * N, pairs);

  // ---- fusion ----
  dim3 gf((N + 127) / 128, 2);
  fusion_score_kernel<<<gf, TPB, 0, stream>>>(x, fw1, fb1, fw2, score, N);
  combine_kernel<<<(N * 32 + TPB - 1) / TPB, TPB, 0, stream>>>(x, score, F0, N);

  int gg = (N + 127) / 128;
  int gs = (N + 7) / 8;  // spmm: 8 half-waves/block, half-wave per row

  // ---- HGCN ----
  gemm128_kernel<<<gg, TPB, 0, stream>>>(F0, hgw + 0 * 16384, nullptr, F1, N);
  spmm_kernel<<<gs, TPB, 0, stream>>>(P, pairs, F1, F2, N, 1, nullptr, nullptr);      // h1
  gemm128_kernel<<<gg, TPB, 0, stream>>>(F2, hgw + 1 * 16384, nullptr, F1, N);
  spmm_kernel<<<gs, TPB, 0, stream>>>(P, pairs, F1, F2, N, 1, nullptr, nullptr);      // h2
  gemm128_kernel<<<gg, TPB, 0, stream>>>(F2, hgw + 2 * 16384, nullptr, F1, N);
  spmm_kernel<<<gs, TPB, 0, stream>>>(P, pairs, F1, outH, N, 1, nullptr, nullptr);    // h3 -> out[0:N]
  spmm_kernel<<<gs, TPB, 0, stream>>>(P + N, pairs, outH, F0, N, 1, nullptr, nullptr); // y

  // ---- LineConv ----
  gemm128_kernel<<<gg, TPB, 0, stream>>>(F0, lgw + 0 * 16384, lgb + 0, F1, N);
  spmm_kernel<<<gs, TPB, 0, stream>>>(P + 2 * N, pairs, F1, F2, N, 0, nullptr, nullptr); // cur1
  gemm128_kernel<<<gg, TPB, 0, stream>>>(F2, lgw + 1 * 16384, lgb + 128, F1, N);
  // cur2 + y + cur1 -> out[N:2N]
  spmm_kernel<<<gs, TPB, 0, stream>>>(P + 2 * N, pairs, F1, outA, N, 0, F0, F2);
}

// Round 3
// 3483.791 us; speedup vs baseline: 1.8047x; 1.8047x over previous
//
#include <hip/hip_runtime.h>
#include <cmath>

#define TPB 256

// ---------------- CSR build ----------------

__global__ void hist_kernel(const int* __restrict__ rows, int E, int* __restrict__ counts) {
  int i = blockIdx.x * TPB + threadIdx.x;
  if (i < E) atomicAdd(&counts[rows[i]], 1);
}

// scan over M counts -> P[0..M] (P[0]=0 after scan3), chunk = 2048/block
__global__ void scan1_kernel(const int* __restrict__ counts, int M,
                             int* __restrict__ P, int* __restrict__ S) {
  __shared__ int lds[TPB];
  int base = blockIdx.x * 2048 + threadIdx.x * 8;
  int v[8];
  int run = 0;
#pragma unroll
  for (int i = 0; i < 8; ++i) {
    int idx = base + i;
    int c = (idx < M) ? counts[idx] : 0;
    run += c;
    v[i] = run;
  }
  lds[threadIdx.x] = run;
  __syncthreads();
  for (int off = 1; off < TPB; off <<= 1) {
    int t = 0;
    if ((int)threadIdx.x >= off) t = lds[threadIdx.x - off];
    __syncthreads();
    if ((int)threadIdx.x >= off) lds[threadIdx.x] += t;
    __syncthreads();
  }
  int excl = (threadIdx.x > 0) ? lds[threadIdx.x - 1] : 0;
#pragma unroll
  for (int i = 0; i < 8; ++i) {
    int idx = base + i;
    if (idx < M) P[idx + 1] = v[i] + excl;
  }
  if (threadIdx.x == TPB - 1) S[blockIdx.x] = lds[TPB - 1];
}

__global__ void scan2_kernel(int* __restrict__ S, int NB) {
  __shared__ int lds[TPB];
  int carry = 0;
  for (int b0 = 0; b0 < NB; b0 += TPB) {
    int i = b0 + threadIdx.x;
    int val = (i < NB) ? S[i] : 0;
    lds[threadIdx.x] = val;
    __syncthreads();
    for (int off = 1; off < TPB; off <<= 1) {
      int t = 0;
      if ((int)threadIdx.x >= off) t = lds[threadIdx.x - off];
      __syncthreads();
      if ((int)threadIdx.x >= off) lds[threadIdx.x] += t;
      __syncthreads();
    }
    int inc = lds[threadIdx.x];
    int tot = lds[TPB - 1];
    if (i < NB) S[i] = inc + carry;
    carry += tot;
    __syncthreads();
  }
}

__global__ void scan3_kernel(int* __restrict__ P, const int* __restrict__ S, int M) {
  int b = blockIdx.x;
  int add = (b == 0) ? 0 : S[b - 1];
  int base = b * 2048;
  for (int i = threadIdx.x; i < 2048; i += TPB) {
    int idx = base + i;
    if (idx < M) P[idx + 1] += add;
  }
  if (b == 0 && threadIdx.x == 0) P[0] = 0;
}

__global__ void copy_int_kernel(const int* __restrict__ src, int* __restrict__ dst, int M) {
  int i = blockIdx.x * TPB + threadIdx.x;
  if (i < M) dst[i] = src[i];
}

__global__ void scatter_kernel(const int* __restrict__ rows, const int* __restrict__ cols,
                               const float* __restrict__ vals, int E,
                               int* __restrict__ cursor, int2* __restrict__ pairs) {
  int i = blockIdx.x * TPB + threadIdx.x;
  if (i < E) {
    int r = rows[i];
    int pos = atomicAdd(&cursor[r], 1);
    pairs[pos] = make_int2(cols[i], __float_as_int(vals[i]));
  }
}

// ---------------- dense GEMM: C[nrows,128] = A @ W (+bias) ----------------
// block 256 thr, tile 128 rows x 128 cols, thread 8x8.
// W staged in 32 KB LDS chunks (k-depth 64).
// Column split {cg*4, 64+cg*4}: 16 lanes sweep all 32 banks -> 2-way LDS
// aliasing (free per m136).
// NOTE (R2 post-mortem): do NOT unroll the k4 loop — unrolling hoists 8
// iterations of a[8] float4 A-loads, VGPR 256 + 1.1 GB spill traffic.

__global__ __launch_bounds__(TPB) void gemm128_kernel(
    const float* __restrict__ A, const float* __restrict__ W,
    const float* __restrict__ bias, float* __restrict__ C, int nrows) {
  __shared__ float sW[64 * 128];
  const int cg = threadIdx.x & 15;
  const int rg = threadIdx.x >> 4;
  const int cA = cg * 4, cB = 64 + cg * 4;
  const int row0 = blockIdx.x * 128 + rg * 8;
  float acc[8][8];
#pragma unroll
  for (int j = 0; j < 8; ++j)
#pragma unroll
    for (int i = 0; i < 8; ++i) acc[j][i] = 0.f;

#pragma unroll 1
  for (int kc = 0; kc < 128; kc += 64) {
    for (int i = threadIdx.x * 4; i < 64 * 128; i += TPB * 4)
      *(float4*)&sW[i] = *(const float4*)&W[kc * 128 + i];
    __syncthreads();
#pragma unroll 1
    for (int k4 = 0; k4 < 64; k4 += 4) {
      float4 a[8];
#pragma unroll
      for (int j = 0; j < 8; ++j) {
        int r = row0 + j;
        a[j] = (r < nrows) ? *(const float4*)&A[(size_t)r * 128 + kc + k4]
                           : make_float4(0.f, 0.f, 0.f, 0.f);
      }
#pragma unroll
      for (int kk = 0; kk < 4; ++kk) {
        float4 w0 = *(const float4*)&sW[(k4 + kk) * 128 + cA];
        float4 w1 = *(const float4*)&sW[(k4 + kk) * 128 + cB];
#pragma unroll
        for (int j = 0; j < 8; ++j) {
          float aj = (kk == 0) ? a[j].x : (kk == 1) ? a[j].y : (kk == 2) ? a[j].z : a[j].w;
          acc[j][0] = fmaf(aj, w0.x, acc[j][0]);
          acc[j][1] = fmaf(aj, w0.y, acc[j][1]);
          acc[j][2] = fmaf(aj, w0.z, acc[j][2]);
          acc[j][3] = fmaf(aj, w0.w, acc[j][3]);
          acc[j][4] = fmaf(aj, w1.x, acc[j][4]);
          acc[j][5] = fmaf(aj, w1.y, acc[j][5]);
          acc[j][6] = fmaf(aj, w1.z, acc[j][6]);
          acc[j][7] = fmaf(aj, w1.w, acc[j][7]);
        }
      }
    }
    __syncthreads();
  }
  float bv[8];
  if (bias) {
    *(float4*)&bv[0] = *(const float4*)&bias[cA];
    *(float4*)&bv[4] = *(const float4*)&bias[cB];
  } else {
#pragma unroll
    for (int i = 0; i < 8; ++i) bv[i] = 0.f;
  }
#pragma unroll
  for (int j = 0; j < 8; ++j) {
    int r = row0 + j;
    if (r < nrows) {
      *(float4*)&C[(size_t)r * 128 + cA] =
          make_float4(acc[j][0] + bv[0], acc[j][1] + bv[1], acc[j][2] + bv[2], acc[j][3] + bv[3]);
      *(float4*)&C[(size_t)r * 128 + cB] =
          make_float4(acc[j][4] + bv[4], acc[j][5] + bv[5], acc[j][6] + bv[6], acc[j][7] + bv[7]);
    }
  }
}

// ---------------- fusion: score[v][n] = w2 . tanh(x[v,n,:] @ W1 + b1) ----------------

__global__ __launch_bounds__(TPB) void fusion_score_kernel(
    const float* __restrict__ x, const float* __restrict__ W1,
    const float* __restrict__ b1, const float* __restrict__ w2,
    float* __restrict__ score, int nrows) {
  __shared__ float sW[64 * 128];
  const int v = blockIdx.y;
  const float* A = x + (size_t)v * nrows * 128;
  const int cg = threadIdx.x & 15;
  const int rg = threadIdx.x >> 4;
  const int cA = cg * 4, cB = 64 + cg * 4;
  const int row0 = blockIdx.x * 128 + rg * 8;
  float acc[8][8];
#pragma unroll
  for (int j = 0; j < 8; ++j)
#pragma unroll
    for (int i = 0; i < 8; ++i) acc[j][i] = 0.f;

#pragma unroll 1
  for (int kc = 0; kc < 128; kc += 64) {
    for (int i = threadIdx.x * 4; i < 64 * 128; i += TPB * 4)
      *(float4*)&sW[i] = *(const float4*)&W1[kc * 128 + i];
    __syncthreads();
#pragma unroll 1
    for (int k4 = 0; k4 < 64; k4 += 4) {
      float4 a[8];
#pragma unroll
      for (int j = 0; j < 8; ++j) {
        int r = row0 + j;
        a[j] = (r < nrows) ? *(const float4*)&A[(size_t)r * 128 + kc + k4]
                           : make_float4(0.f, 0.f, 0.f, 0.f);
      }
#pragma unroll
      for (int kk = 0; kk < 4; ++kk) {
        float4 w0 = *(const float4*)&sW[(k4 + kk) * 128 + cA];
        float4 w1 = *(const float4*)&sW[(k4 + kk) * 128 + cB];
#pragma unroll
        for (int j = 0; j < 8; ++j) {
          float aj = (kk == 0) ? a[j].x : (kk == 1) ? a[j].y : (kk == 2) ? a[j].z : a[j].w;
          acc[j][0] = fmaf(aj, w0.x, acc[j][0]);
          acc[j][1] = fmaf(aj, w0.y, acc[j][1]);
          acc[j][2] = fmaf(aj, w0.z, acc[j][2]);
          acc[j][3] = fmaf(aj, w0.w, acc[j][3]);
          acc[j][4] = fmaf(aj, w1.x, acc[j][4]);
          acc[j][5] = fmaf(aj, w1.y, acc[j][5]);
          acc[j][6] = fmaf(aj, w1.z, acc[j][6]);
          acc[j][7] = fmaf(aj, w1.w, acc[j][7]);
        }
      }
    }
    __syncthreads();
  }
  float bb[8], ww[8];
  *(float4*)&bb[0] = *(const float4*)&b1[cA];
  *(float4*)&bb[4] = *(const float4*)&b1[cB];
  *(float4*)&ww[0] = *(const float4*)&w2[cA];
  *(float4*)&ww[4] = *(const float4*)&w2[cB];
#pragma unroll
  for (int j = 0; j < 8; ++j) {
    float p = 0.f;
#pragma unroll
    for (int i = 0; i < 8; ++i) p += tanhf(acc[j][i] + bb[i]) * ww[i];
#pragma unroll
    for (int off = 8; off > 0; off >>= 1) p += __shfl_down(p, off, 16);
    if (cg == 0 && row0 + j < nrows) score[(size_t)v * nrows + row0 + j] = p;
  }
}

// softmax over 2 views + weighted sum (b2 cancels in the 2-way softmax)
__global__ void combine_kernel(const float* __restrict__ x, const float* __restrict__ score,
                               float* __restrict__ fused, int nrows) {
  int i = blockIdx.x * TPB + threadIdx.x;  // over nrows*32 float4s
  if (i >= nrows * 32) return;
  int n = i >> 5;
  float s0 = score[n], s1 = score[nrows + n];
  float m = fmaxf(s0, s1);
  float e0 = expf(s0 - m), e1 = expf(s1 - m);
  float inv = 1.f / (e0 + e1);
  float w0 = e0 * inv, w1 = e1 * inv;
  float4 a = ((const float4*)x)[i];
  float4 b = ((const float4*)x)[(size_t)nrows * 32 + i];
  ((float4*)fused)[i] = make_float4(w0 * a.x + w1 * b.x, w0 * a.y + w1 * b.y,
                                    w0 * a.z + w1 * b.z, w0 * a.w + w1 * b.w);
}

// ---------------- spmm: y[r,:] = (relu?) sum val * x[col,:] (+add0 +add1) ----------------
// one 32-lane half-wave per row; lanes hold float4 (128 cols / 32 lanes).

__global__ __launch_bounds__(TPB) void spmm_kernel(
    const int* __restrict__ ptr, const int2* __restrict__ pairs,
    const float* __restrict__ x, float* __restrict__ y, int nrows, int do_relu,
    const float* __restrict__ add0, const float* __restrict__ add1) {
  int row = (blockIdx.x * TPB + threadIdx.x) >> 5;
  int hl = threadIdx.x & 31;
  if (row >= nrows) return;
  int start = ptr[row], end = ptr[row + 1];
  float ax = 0.f, ay = 0.f, az = 0.f, aw = 0.f;
  for (int j = start; j < end; j += 32) {
    int nrem = end - j;
    if (nrem > 32) nrem = 32;
    int2 pr = make_int2(0, 0);
    if (hl < nrem) pr = pairs[j + hl];
    for (int t = 0; t < nrem; ++t) {
      int c = __shfl(pr.x, t, 32);
      float v = __int_as_float(__shfl(pr.y, t, 32));
      const float4 xv = *(const float4*)&x[(size_t)c * 128 + hl * 4];
      ax = fmaf(v, xv.x, ax);
      ay = fmaf(v, xv.y, ay);
      az = fmaf(v, xv.z, az);
      aw = fmaf(v, xv.w, aw);
    }
  }
  if (do_relu) {
    ax = fmaxf(ax, 0.f); ay = fmaxf(ay, 0.f);
    az = fmaxf(az, 0.f); aw = fmaxf(aw, 0.f);
  }
  size_t o = (size_t)row * 128 + hl * 4;
  if (add0) { float4 t = *(const float4*)&add0[o]; ax += t.x; ay += t.y; az += t.z; aw += t.w; }
  if (add1) { float4 t = *(const float4*)&add1[o]; ax += t.x; ay += t.y; az += t.z; aw += t.w; }
  *(float4*)&y[o] = make_float4(ax, ay, az, aw);
}

// ---------------- launch ----------------

extern "C" void kernel_launch(void* const* d_in, const int* in_sizes, int n_in,
                              void* d_out, int out_size, void* d_ws, size_t ws_size,
                              hipStream_t stream) {
  const float* x   = (const float*)d_in[0];
  const float* fw1 = (const float*)d_in[1];
  const float* fb1 = (const float*)d_in[2];
  const float* fw2 = (const float*)d_in[3];
  // d_in[4] = fusion_b2: cancels in 2-way softmax
  const float* hgw = (const float*)d_in[5];
  const float* lgw = (const float*)d_in[6];
  const float* lgb = (const float*)d_in[7];
  const float* c1v = (const float*)d_in[8];
  const float* c2v = (const float*)d_in[9];
  const float* lgv = (const float*)d_in[10];
  const int* c1r = (const int*)d_in[11];
  const int* c1c = (const int*)d_in[12];
  const int* c2r = (const int*)d_in[13];
  const int* c2c = (const int*)d_in[14];
  const int* lgr = (const int*)d_in[15];
  const int* lgc = (const int*)d_in[16];

  const int N = in_sizes[0] / 256;  // x is [2,N,128]
  const int E = in_sizes[8];
  const int M = 3 * N;

  char* ws = (char*)d_ws;
  size_t off = 0;
  auto alloc = [&](size_t bytes) -> void* {
    void* p = ws + off;
    off += (bytes + 511) & ~(size_t)511;
    return p;
  };
  int* P      = (int*)alloc((size_t)(M + 1) * 4);
  int* S      = (int*)alloc((size_t)4096 * 4);
  int* Q      = (int*)alloc((size_t)M * 4);
  int* counts = (int*)alloc((size_t)M * 4);
  int2* pairs = (int2*)alloc((size_t)3 * E * 8);
  float* score = (float*)alloc((size_t)2 * N * 4);
  float* F0 = (float*)alloc((size_t)N * 128 * 4);
  float* F1 = (float*)alloc((size_t)N * 128 * 4);
  float* F2 = (float*)alloc((size_t)N * 128 * 4);
  float* outH = (float*)d_out;
  float* outA = (float*)d_out + (size_t)N * 128;

  // ---- CSR build for [coef1 | coef2 | lg] concatenated ----
  hipMemsetAsync(counts, 0, (size_t)M * 4, stream);
  int gE = (E + TPB - 1) / TPB;
  hist_kernel<<<gE, TPB, 0, stream>>>(c1r, E, counts + 0);
  hist_kernel<<<gE, TPB, 0, stream>>>(c2r, E, counts + N);
  hist_kernel<<<gE, TPB, 0, stream>>>(lgr, E, counts + 2 * N);
  int NB = (M + 2047) / 2048;
  scan1_kernel<<<NB, TPB, 0, stream>>>(counts, M, P, S);
  scan2_kernel<<<1, TPB, 0, stream>>>(S, NB);
  scan3_kernel<<<NB, TPB, 0, stream>>>(P, S, M);
  copy_int_kernel<<<(M + TPB - 1) / TPB, TPB, 0, stream>>>(P, Q, M);
  scatter_kernel<<<gE, TPB, 0, stream>>>(c1r, c1c, c1v, E, Q + 0, pairs);
  scatter_kernel<<<gE, TPB, 0, stream>>>(c2r, c2c, c2v, E, Q + N, pairs);
  scatter_kernel<<<gE, TPB, 0, stream>>>(lgr, lgc, lgv, E, Q + 2 * N, pairs);

  // ---- fusion ----
  dim3 gf((N + 127) / 128, 2);
  fusion_score_kernel<<<gf, TPB, 0, stream>>>(x, fw1, fb1, fw2, score, N);
  combine_kernel<<<(N * 32 + TPB - 1) / TPB, TPB, 0, stream>>>(x, score, F0, N);

  int gg = (N + 127) / 128;
  int gs = (N + 7) / 8;  // spmm: 8 half-waves/block, half-wave per row

  // ---- HGCN ----
  gemm128_kernel<<<gg, TPB, 0, stream>>>(F0, hgw + 0 * 16384, nullptr, F1, N);
  spmm_kernel<<<gs, TPB, 0, stream>>>(P, pairs, F1, F2, N, 1, nullptr, nullptr);      // h1
  gemm128_kernel<<<gg, TPB, 0, stream>>>(F2, hgw + 1 * 16384, nullptr, F1, N);
  spmm_kernel<<<gs, TPB, 0, stream>>>(P, pairs, F1, F2, N, 1, nullptr, nullptr);      // h2
  gemm128_kernel<<<gg, TPB, 0, stream>>>(F2, hgw + 2 * 16384, nullptr, F1, N);
  spmm_kernel<<<gs, TPB, 0, stream>>>(P, pairs, F1, outH, N, 1, nullptr, nullptr);    // h3 -> out[0:N]
  spmm_kernel<<<gs, TPB, 0, stream>>>(P + N, pairs, outH, F0, N, 1, nullptr, nullptr); // y

  // ---- LineConv ----
  gemm128_kernel<<<gg, TPB, 0, stream>>>(F0, lgw + 0 * 16384, lgb + 0, F1, N);
  spmm_kernel<<<gs, TPB, 0, stream>>>(P + 2 * N, pairs, F1, F2, N, 0, nullptr, nullptr); // cur1
  gemm128_kernel<<<gg, TPB, 0, stream>>>(F2, lgw + 1 * 16384, lgb + 128, F1, N);
  // cur2 + y + cur1 -> out[N:2N]
  spmm_kernel<<<gs, TPB, 0, stream>>>(P + 2 * N, pairs, F1, outA, N, 0, F0, F2);
}